// Round 4
// baseline (326.658 us; speedup 1.0000x reference)
//
#include <hip/hip_runtime.h>

typedef float floatx4 __attribute__((ext_vector_type(4)));
typedef __bf16 bf16x8 __attribute__((ext_vector_type(8)));
using u16 = unsigned short;
using u32 = unsigned int;

#define GLOBAL_AS __attribute__((address_space(1)))
#define LDS_AS    __attribute__((address_space(3)))

// ---------------- conversion: x fp32 -> bf16 (RNE) ----------------
__global__ void cvt_x_kernel(const float* __restrict__ x, u16* __restrict__ xb, int n8) {
  int stride = gridDim.x * blockDim.x;
  for (int i = blockIdx.x * blockDim.x + threadIdx.x; i < n8; i += stride) {
    const float4* p = (const float4*)(x + (size_t)i * 8);
    float4 a = p[0], b = p[1];
    float v[8] = {a.x, a.y, a.z, a.w, b.x, b.y, b.z, b.w};
    u32 r[8];
#pragma unroll
    for (int j = 0; j < 8; ++j) {
      u32 u = __float_as_uint(v[j]);
      r[j] = (u + 0x7FFFu + ((u >> 16) & 1u)) >> 16;  // RNE
    }
    uint4 o;
    o.x = r[0] | (r[1] << 16);
    o.y = r[2] | (r[3] << 16);
    o.z = r[4] | (r[5] << 16);
    o.w = r[6] | (r[7] << 16);
    *(uint4*)(xb + (size_t)i * 8) = o;
  }
}

// ---------------- quantize: w fp32 -> ternary {-1,0,+1} as bf16 bits ----------------
__global__ void quant_w_kernel(const float* __restrict__ w, u16* __restrict__ wb, int n8) {
  int stride = gridDim.x * blockDim.x;
  for (int i = blockIdx.x * blockDim.x + threadIdx.x; i < n8; i += stride) {
    const float4* p = (const float4*)(w + (size_t)i * 8);
    float4 a = p[0], b = p[1];
    float v[8] = {a.x, a.y, a.z, a.w, b.x, b.y, b.z, b.w};
    u32 r[8];
#pragma unroll
    for (int j = 0; j < 8; ++j) {
      r[j] = (v[j] > 0.05f) ? 0x3F80u : ((v[j] < -0.05f) ? -1.0f == -1.0f ? 0xBF80u : 0u : 0u);
    }
    uint4 o;
    o.x = r[0] | (r[1] << 16);
    o.y = r[2] | (r[3] << 16);
    o.z = r[4] | (r[5] << 16);
    o.w = r[6] | (r[7] << 16);
    *(uint4*)(wb + (size_t)i * 8) = o;
  }
}

// ---------------- 256x256 bf16 MFMA GEMM, 1-step register pipeline ----------------
// A: [M][K] bf16 (x), B: [N][K] bf16 (ternary W), out[m][n] = sum_k A[m][k]*B[n][k] + bias[n]
// 8 waves (2M x 4N), per-wave 128x64. LDS: 4 ring slots of (A[256][32]+B[256][32]) = 4x32KB,
// fragment-permuted via pre-permuted GLOBAL source (LDS dest linear -> global_load_lds ok;
// reads are wave_base + frag*1024 + lane*16 -> zero bank conflicts).
// Pipeline per step s: stage slot s+3 | prefetch frags(s+1) into ping-pong regs |
// lgkmcnt(12) (drains frags(s), issued LAST step -> ~free) | 32 MFMA | vmcnt(4) | barrier.
// Safety: stage at step s writes slot (s-1)&3 whose reads drained before barrier end-of-(s-1);
// vmcnt(4) at end of s-1 leaves only stage(s+2) in flight -> slot s+1 landed for prefetch at s.
__global__ __launch_bounds__(512, 2) void gemm_bin_pipe(
    const u16* __restrict__ A, const u16* __restrict__ B,
    const float* __restrict__ bias, float* __restrict__ C,
    int M, int N, int K) {
  __shared__ u16 lds[65536];  // 128 KiB

  const int tid = threadIdx.x;
  const int w = tid >> 6, l = tid & 63;
  const int wr = w >> 2, wc = w & 3;       // 2x4 wave grid
  const int r = l & 15;

  const int nbn = N >> 8;
  int wg = blockIdx.x;
  const int nwg = gridDim.x;
  if ((nwg & 7) == 0) wg = (wg & 7) * (nwg >> 3) + (wg >> 3);  // XCD swizzle (bijective)
  const int bm = wg / nbn, bn = wg % nbn;

  const int NSTEPS = K >> 5;

  // fragment-permuted staging source: thread t -> row 16*(t>>6)+(t&15), k 8*((t>>4)&3)
  const int prow = ((tid >> 6) << 4) + (tid & 15);
  const int pk = ((tid >> 4) & 3) << 3;
  const size_t Abase = (size_t)(bm * 256 + prow) * K + pk;
  const size_t Bbase = (size_t)(bn * 256 + prow) * K + pk;
  const size_t chunkStride = (size_t)128 * K;

  // LDS read bases (u16 elems): lane-sequential 16B/lane
  const u16* const ldsA = lds + wr * 4096 + l * 8;
  const u16* const ldsB = lds + 8192 + wc * 2048 + l * 8;

  floatx4 acc[8][4] = {};
  bf16x8 afA[8], bfA[4], afB[8], bfB[4];  // ping-pong fragment sets

#define GLOAD(gptr, ldsoff)                                                    \
  __builtin_amdgcn_global_load_lds((const GLOBAL_AS void*)(gptr),              \
                                   (LDS_AS void*)(lds + (ldsoff)), 16, 0, 0)

  // prologue: stage steps 0..3 into slots 0..3
  for (int u = 0; u < 4; ++u) {
    const int so = u * 16384;
    const u16* ga = A + Abase + (size_t)u * 32;
    const u16* gb = B + Bbase + (size_t)u * 32;
    GLOAD(ga, so + tid * 8);
    GLOAD(ga + chunkStride, so + 4096 + tid * 8);
    GLOAD(gb, so + 8192 + tid * 8);
    GLOAD(gb + chunkStride, so + 12288 + tid * 8);
  }
  asm volatile("s_waitcnt vmcnt(8)" ::: "memory");  // slots 0,1 landed
  __builtin_amdgcn_s_barrier();
#pragma unroll
  for (int m = 0; m < 8; ++m) afA[m] = *(const bf16x8*)(ldsA + m * 512);
#pragma unroll
  for (int n = 0; n < 4; ++n) bfA[n] = *(const bf16x8*)(ldsB + n * 512);

#define STEP(s, CURA, CURB, NXTA, NXTB)                                        \
  {                                                                            \
    if ((s) >= 1 && (s) + 3 < NSTEPS) {                                        \
      const int sd_ = (((s) + 3) & 3) * 16384;                                 \
      const u16* ga_ = A + Abase + (size_t)((s) + 3) * 32;                     \
      const u16* gb_ = B + Bbase + (size_t)((s) + 3) * 32;                     \
      GLOAD(ga_, sd_ + tid * 8);                                               \
      GLOAD(ga_ + chunkStride, sd_ + 4096 + tid * 8);                          \
      GLOAD(gb_, sd_ + 8192 + tid * 8);                                        \
      GLOAD(gb_ + chunkStride, sd_ + 12288 + tid * 8);                         \
    }                                                                          \
    const int son_ = (((s) + 1) & 3) * 16384;                                  \
    _Pragma("unroll")                                                          \
    for (int m = 0; m < 8; ++m) NXTA[m] = *(const bf16x8*)(ldsA + son_ + m * 512); \
    _Pragma("unroll")                                                          \
    for (int n = 0; n < 4; ++n) NXTB[n] = *(const bf16x8*)(ldsB + son_ + n * 512); \
    asm volatile("s_waitcnt lgkmcnt(12)" ::: "memory");                        \
    __builtin_amdgcn_sched_barrier(0);                                         \
    __builtin_amdgcn_s_setprio(1);                                             \
    _Pragma("unroll")                                                          \
    for (int m = 0; m < 8; ++m)                                                \
      _Pragma("unroll")                                                        \
      for (int n = 0; n < 4; ++n)                                              \
        acc[m][n] = __builtin_amdgcn_mfma_f32_16x16x32_bf16(CURA[m], CURB[n],  \
                                                            acc[m][n], 0, 0, 0); \
    __builtin_amdgcn_s_setprio(0);                                             \
    __builtin_amdgcn_sched_barrier(0);                                         \
    if ((s) + 1 < NSTEPS) {                                                    \
      if ((s) + 3 < NSTEPS) asm volatile("s_waitcnt vmcnt(4)" ::: "memory");   \
      else                  asm volatile("s_waitcnt vmcnt(0)" ::: "memory");   \
      __builtin_amdgcn_s_barrier();                                            \
    }                                                                          \
  }

  for (int t = 0; t < (NSTEPS >> 1); ++t) {
    const int s0 = t << 1;
    STEP(s0,     afA, bfA, afB, bfB);
    STEP(s0 + 1, afB, bfB, afA, bfA);
  }
#undef STEP
#undef GLOAD

  // ---- epilogue: C/D layout col = l&15, row = (l>>4)*4 + q ----
  const int g = l >> 4;
  const int colb = bn * 256 + wc * 64;
  float bv[4];
#pragma unroll
  for (int n = 0; n < 4; ++n) bv[n] = bias[colb + n * 16 + r];
  const int rowb0 = bm * 256 + wr * 128;
#pragma unroll
  for (int m = 0; m < 8; ++m) {
    const int rowb = rowb0 + m * 16 + g * 4;
#pragma unroll
    for (int n = 0; n < 4; ++n) {
      const int col = colb + n * 16 + r;
      float* cp = C + (size_t)rowb * N + col;
#pragma unroll
      for (int q = 0; q < 4; ++q) cp[(size_t)q * N] = acc[m][n][q] + bv[n];
    }
  }
}

// ---------------- fallback: slow but correct ----------------
__global__ void gemm_naive_kernel(const float* __restrict__ x, const float* __restrict__ wgt,
                                  const float* __restrict__ bias, float* __restrict__ out,
                                  int M, int N, int K) {
  long long idx = (long long)blockIdx.x * blockDim.x + threadIdx.x;
  if (idx >= (long long)M * N) return;
  int o = (int)(idx % N);
  int m = (int)(idx / N);
  const float* xr = x + (size_t)m * K;
  const float* wr = wgt + (size_t)o * K;
  float s = 0.f;
  for (int i = 0; i < K; ++i) {
    float wv = wr[i];
    float t = (wv > 0.05f) ? 1.f : ((wv < -0.05f) ? -1.f : 0.f);
    s = fmaf(xr[i], t, s);
  }
  out[idx] = s + bias[o];
}

extern "C" void kernel_launch(void* const* d_in, const int* in_sizes, int n_in,
                              void* d_out, int out_size, void* d_ws, size_t ws_size,
                              hipStream_t stream) {
  const float* x    = (const float*)d_in[0];
  const float* wgt  = (const float*)d_in[1];
  const float* bias = (const float*)d_in[2];
  float* out = (float*)d_out;

  const int N = in_sizes[2];                 // out features
  const int K = in_sizes[1] / N;             // in features
  const int M = in_sizes[0] / K;             // batch rows

  const size_t need = ((size_t)M * K + (size_t)N * K) * sizeof(u16);
  if (ws_size >= need && (M % 256 == 0) && (N % 256 == 0) && (K % 64 == 0) && K >= 256) {
    u16* xb = (u16*)d_ws;
    u16* wb = xb + (size_t)M * K;
    const int nx8 = (M * K) / 8;
    const int nw8 = (N * K) / 8;
    cvt_x_kernel<<<2048, 256, 0, stream>>>(x, xb, nx8);
    quant_w_kernel<<<2048, 256, 0, stream>>>(wgt, wb, nw8);
    const int grid = (M / 256) * (N / 256);
    gemm_bin_pipe<<<grid, 512, 0, stream>>>(xb, wb, bias, out, M, N, K);
  } else {
    const long long total = (long long)M * N;
    gemm_naive_kernel<<<(unsigned)((total + 255) / 256), 256, 0, stream>>>(x, wgt, bias, out, M, N, K);
  }
}

// Round 5
// 307.362 us; speedup vs baseline: 1.0628x; 1.0628x over previous
//
#include <hip/hip_runtime.h>

typedef float floatx4 __attribute__((ext_vector_type(4)));
typedef __bf16 bf16x8 __attribute__((ext_vector_type(8)));
using u16 = unsigned short;
using u32 = unsigned int;

#define GLOBAL_AS __attribute__((address_space(1)))
#define LDS_AS    __attribute__((address_space(3)))

// ---------------- conversion: x fp32 -> bf16 (RNE) ----------------
__global__ void cvt_x_kernel(const float* __restrict__ x, u16* __restrict__ xb, int n8) {
  int stride = gridDim.x * blockDim.x;
  for (int i = blockIdx.x * blockDim.x + threadIdx.x; i < n8; i += stride) {
    const float4* p = (const float4*)(x + (size_t)i * 8);
    float4 a = p[0], b = p[1];
    float v[8] = {a.x, a.y, a.z, a.w, b.x, b.y, b.z, b.w};
    u32 r[8];
#pragma unroll
    for (int j = 0; j < 8; ++j) {
      u32 u = __float_as_uint(v[j]);
      r[j] = (u + 0x7FFFu + ((u >> 16) & 1u)) >> 16;  // RNE
    }
    uint4 o;
    o.x = r[0] | (r[1] << 16);
    o.y = r[2] | (r[3] << 16);
    o.z = r[4] | (r[5] << 16);
    o.w = r[6] | (r[7] << 16);
    *(uint4*)(xb + (size_t)i * 8) = o;
  }
}

// ---------------- quantize: w fp32 -> ternary {-1,0,+1} as bf16 bits ----------------
__global__ void quant_w_kernel(const float* __restrict__ w, u16* __restrict__ wb, int n8) {
  int stride = gridDim.x * blockDim.x;
  for (int i = blockIdx.x * blockDim.x + threadIdx.x; i < n8; i += stride) {
    const float4* p = (const float4*)(w + (size_t)i * 8);
    float4 a = p[0], b = p[1];
    float v[8] = {a.x, a.y, a.z, a.w, b.x, b.y, b.z, b.w};
    u32 r[8];
#pragma unroll
    for (int j = 0; j < 8; ++j) {
      r[j] = (v[j] > 0.05f) ? 0x3F80u : ((v[j] < -0.05f) ? 0xBF80u : 0u);
    }
    uint4 o;
    o.x = r[0] | (r[1] << 16);
    o.y = r[2] | (r[3] << 16);
    o.z = r[4] | (r[5] << 16);
    o.w = r[6] | (r[7] << 16);
    *(uint4*)(wb + (size_t)i * 8) = o;
  }
}

// ---------------- m201-template 256x256 BK=64 4-phase/K-tile bf16 GEMM ----------------
// out[m][n] = sum_k A[m][k]*B[n][k] + bias[n]; A[M][K], B[N][K] bf16.
// 8 waves (2M x 4N), per-wave 128x64. LDS: 2 dbuf x 64KB; each buffer:
//   A chunk c (rows c*128..): byte c*16384 + mg*2048 + j*1024 + l*16  (mg=0..7, j=ksub 0..1)
//   B (ng-outer): byte 32768 + (ng>>1)*16384 + wc*4096 + (ng&1)*2048 + j*1024 + l*16
// Fragment-permuted global source keeps LDS dest linear (global_load_lds ok) and
// fragment reads lane-sequential (0 bank conflicts, verified r3).
// Phases per K-tile: P1{read af0-3+bflo(12), stage A_lo', Q(m0,n01)} P2{bfhi(4),
// B_nlo', Q(m0,n23)} P3{af4-7(8), B_nhi', Q(m1,n01)} P4{0, A_hi', Q(m1,n23)}.
// vmcnt(4) at EVERY phase end (never 0 in steady state): FIFO-lag-2 drains the
// half staged 2 phases earlier; every half lands >=1 phase before first read.
__global__ __launch_bounds__(512, 2) void gemm_bin_m201(
    const u16* __restrict__ A, const u16* __restrict__ B,
    const float* __restrict__ bias, float* __restrict__ C,
    int M, int N, int K) {
  __shared__ u16 lds[65536];  // 128 KiB

  const int tid = threadIdx.x;
  const int w = tid >> 6, l = tid & 63;
  const int wr = w >> 2, wc = w & 3;       // 2x4 wave grid
  const int r = l & 15;

  const int nbn = N >> 8;
  int wg = blockIdx.x;
  const int nwg = gridDim.x;
  if ((nwg & 7) == 0) wg = (wg & 7) * (nwg >> 3) + (wg >> 3);  // XCD swizzle (bijective)
  const int bm = wg / nbn, bn = wg % nbn;

  const int T = K >> 6;  // K-tiles of 64

  // fragment-permuted staging source (one gload = 8KB span = 64 rows x 64 k):
  // thread t -> row 16*(t>>7)+(t&15), k = 32*((t>>6)&1) + 8*((t>>4)&3)
  const int srow = ((tid >> 7) << 4) + (tid & 15);
  const int skk = (((tid >> 6) & 1) << 5) + (((tid >> 4) & 3) << 3);
  const size_t aLo0 = (size_t)(bm * 256 + srow) * K + skk;
  // B gload pair p covers wc = 2p + (t>>8): row = wc*64 + ng*16 + (t&15)
  const int brow = ((tid >> 8) << 6) + (((tid >> 7) & 1) << 4) + (tid & 15);
  const size_t bLo0 = (size_t)(bn * 256 + brow) * K + skk;
  const size_t cs = (size_t)128 * K;  // chunk / pair stride

  floatx4 acc[8][4] = {};
  bf16x8 af[8], bflo[4], bfhi[4];

#define GLOAD(gptr, u16off)                                                    \
  __builtin_amdgcn_global_load_lds((const GLOBAL_AS void*)(gptr),              \
                                   (LDS_AS void*)(lds + (u16off)), 16, 0, 0)
#define BARRIER __builtin_amdgcn_s_barrier()
#define LGKM0  do { asm volatile("s_waitcnt lgkmcnt(0)" ::: "memory");         \
                    __builtin_amdgcn_sched_barrier(0); } while (0)

  // prologue: stage tile 0 into buf0, order A_lo, B_nlo, B_nhi, A_hi
  GLOAD(A + aLo0,               0 + tid * 8);
  GLOAD(A + aLo0 + cs,       8192 + tid * 8);
  GLOAD(B + bLo0,           16384 + tid * 8);
  GLOAD(B + bLo0 + cs,      20480 + tid * 8);
  GLOAD(B + bLo0 + (size_t)32 * K,      24576 + tid * 8);
  GLOAD(B + bLo0 + (size_t)32 * K + cs, 28672 + tid * 8);
  GLOAD(A + aLo0 + (size_t)64 * K,       4096 + tid * 8);
  GLOAD(A + aLo0 + (size_t)64 * K + cs, 12288 + tid * 8);
  asm volatile("s_waitcnt vmcnt(4)" ::: "memory");  // A_lo,B_nlo landed
  BARRIER;

  for (int t = 0; t < T; ++t) {
    const int bufc = (t & 1) << 15;      // current buffer (u16 elems)
    const int bufn = bufc ^ 32768;       // next buffer
    const bool doSt = (t + 1 < T);
    const size_t kadv = (size_t)(t + 1) << 6;

    const u16* afp = lds + bufc + wr * 8192 + l * 8;
    const u16* bfp = lds + bufc + 16384 + wc * 2048 + l * 8;

    // ================= P1: af[0..7]? no - af[0..3]x2j (8) + bflo (4) =================
#pragma unroll
    for (int i = 0; i < 8; ++i) af[i] = *(const bf16x8*)(afp + i * 512);
#pragma unroll
    for (int i = 0; i < 4; ++i) bflo[i] = *(const bf16x8*)(bfp + i * 512);
    if (doSt) {
      GLOAD(A + aLo0 + kadv,      bufn + 0 + tid * 8);
      GLOAD(A + aLo0 + cs + kadv, bufn + 8192 + tid * 8);
    }
    asm volatile("s_waitcnt lgkmcnt(8)" ::: "memory");  // pre-drain 4 of 12
    BARRIER;
    LGKM0;
    __builtin_amdgcn_s_setprio(1);
#pragma unroll
    for (int j = 0; j < 2; ++j)
#pragma unroll
      for (int mg = 0; mg < 4; ++mg)
#pragma unroll
        for (int ng = 0; ng < 2; ++ng)
          acc[mg][ng] = __builtin_amdgcn_mfma_f32_16x16x32_bf16(
              af[mg * 2 + j], bflo[ng * 2 + j], acc[mg][ng], 0, 0, 0);
    __builtin_amdgcn_s_setprio(0);
    if (doSt) asm volatile("s_waitcnt vmcnt(4)" ::: "memory");
    else      asm volatile("s_waitcnt vmcnt(2)" ::: "memory");
    BARRIER;

    // ================= P2: bfhi (4) ; stage B_nlo' ; Q(m0, n23) =================
#pragma unroll
    for (int i = 0; i < 4; ++i) bfhi[i] = *(const bf16x8*)(bfp + 8192 + i * 512);
    if (doSt) {
      GLOAD(B + bLo0 + kadv,      bufn + 16384 + tid * 8);
      GLOAD(B + bLo0 + cs + kadv, bufn + 20480 + tid * 8);
    }
    BARRIER;
    LGKM0;
    __builtin_amdgcn_s_setprio(1);
#pragma unroll
    for (int j = 0; j < 2; ++j)
#pragma unroll
      for (int mg = 0; mg < 4; ++mg)
#pragma unroll
        for (int ng = 0; ng < 2; ++ng)
          acc[mg][2 + ng] = __builtin_amdgcn_mfma_f32_16x16x32_bf16(
              af[mg * 2 + j], bfhi[ng * 2 + j], acc[mg][2 + ng], 0, 0, 0);
    __builtin_amdgcn_s_setprio(0);
    if (doSt) asm volatile("s_waitcnt vmcnt(4)" ::: "memory");
    else      asm volatile("s_waitcnt vmcnt(0)" ::: "memory");
    BARRIER;

    // ================= P3: af[4..7]x2j (8) ; stage B_nhi' ; Q(m1, n01) =================
#pragma unroll
    for (int i = 0; i < 8; ++i) af[i] = *(const bf16x8*)(afp + 4096 + i * 512);
    if (doSt) {
      GLOAD(B + bLo0 + (size_t)32 * K + kadv,      bufn + 24576 + tid * 8);
      GLOAD(B + bLo0 + (size_t)32 * K + cs + kadv, bufn + 28672 + tid * 8);
    }
    asm volatile("s_waitcnt lgkmcnt(4)" ::: "memory");  // pre-drain 4 of 8
    BARRIER;
    LGKM0;
    __builtin_amdgcn_s_setprio(1);
#pragma unroll
    for (int j = 0; j < 2; ++j)
#pragma unroll
      for (int mg = 0; mg < 4; ++mg)
#pragma unroll
        for (int ng = 0; ng < 2; ++ng)
          acc[4 + mg][ng] = __builtin_amdgcn_mfma_f32_16x16x32_bf16(
              af[mg * 2 + j], bflo[ng * 2 + j], acc[4 + mg][ng], 0, 0, 0);
    __builtin_amdgcn_s_setprio(0);
    if (doSt) asm volatile("s_waitcnt vmcnt(4)" ::: "memory");
    BARRIER;

    // ================= P4: 0 reads ; stage A_hi' ; Q(m1, n23) =================
    if (doSt) {
      GLOAD(A + aLo0 + (size_t)64 * K + kadv,      bufn + 4096 + tid * 8);
      GLOAD(A + aLo0 + (size_t)64 * K + cs + kadv, bufn + 12288 + tid * 8);
    }
    BARRIER;
    __builtin_amdgcn_s_setprio(1);
#pragma unroll
    for (int j = 0; j < 2; ++j)
#pragma unroll
      for (int mg = 0; mg < 4; ++mg)
#pragma unroll
        for (int ng = 0; ng < 2; ++ng)
          acc[4 + mg][2 + ng] = __builtin_amdgcn_mfma_f32_16x16x32_bf16(
              af[mg * 2 + j], bfhi[ng * 2 + j], acc[4 + mg][2 + ng], 0, 0, 0);
    __builtin_amdgcn_s_setprio(0);
    if (doSt) asm volatile("s_waitcnt vmcnt(4)" ::: "memory");
    BARRIER;
  }
#undef GLOAD
#undef BARRIER
#undef LGKM0

  // ---- epilogue: C/D layout col = l&15, row = (l>>4)*4 + q (m89/m91-verified) ----
  const int g = l >> 4;
  const int colb = bn * 256 + wc * 64;
  float bv[4];
#pragma unroll
  for (int n = 0; n < 4; ++n) bv[n] = bias[colb + n * 16 + r];
  const int rowb0 = bm * 256 + wr * 128;
#pragma unroll
  for (int m = 0; m < 8; ++m) {
    const int rowb = rowb0 + m * 16 + g * 4;
#pragma unroll
    for (int n = 0; n < 4; ++n) {
      const int col = colb + n * 16 + r;
      float* cp = C + (size_t)rowb * N + col;
#pragma unroll
      for (int q = 0; q < 4; ++q) cp[(size_t)q * N] = acc[m][n][q] + bv[n];
    }
  }
}

// ---------------- fallback: slow but correct ----------------
__global__ void gemm_naive_kernel(const float* __restrict__ x, const float* __restrict__ wgt,
                                  const float* __restrict__ bias, float* __restrict__ out,
                                  int M, int N, int K) {
  long long idx = (long long)blockIdx.x * blockDim.x + threadIdx.x;
  if (idx >= (long long)M * N) return;
  int o = (int)(idx % N);
  int m = (int)(idx / N);
  const float* xr = x + (size_t)m * K;
  const float* wr = wgt + (size_t)o * K;
  float s = 0.f;
  for (int i = 0; i < K; ++i) {
    float wv = wr[i];
    float t = (wv > 0.05f) ? 1.f : ((wv < -0.05f) ? -1.f : 0.f);
    s = fmaf(xr[i], t, s);
  }
  out[idx] = s + bias[o];
}

extern "C" void kernel_launch(void* const* d_in, const int* in_sizes, int n_in,
                              void* d_out, int out_size, void* d_ws, size_t ws_size,
                              hipStream_t stream) {
  const float* x    = (const float*)d_in[0];
  const float* wgt  = (const float*)d_in[1];
  const float* bias = (const float*)d_in[2];
  float* out = (float*)d_out;

  const int N = in_sizes[2];                 // out features
  const int K = in_sizes[1] / N;             // in features
  const int M = in_sizes[0] / K;             // batch rows

  const size_t need = ((size_t)M * K + (size_t)N * K) * sizeof(u16);
  if (ws_size >= need && (M % 256 == 0) && (N % 256 == 0) && (K % 64 == 0) && K >= 128) {
    u16* xb = (u16*)d_ws;
    u16* wb = xb + (size_t)M * K;
    const int nx8 = (M * K) / 8;
    const int nw8 = (N * K) / 8;
    cvt_x_kernel<<<2048, 256, 0, stream>>>(x, xb, nx8);
    quant_w_kernel<<<2048, 256, 0, stream>>>(wgt, wb, nw8);
    const int grid = (M / 256) * (N / 256);
    gemm_bin_m201<<<grid, 512, 0, stream>>>(xb, wb, bias, out, M, N, K);
  } else {
    const long long total = (long long)M * N;
    gemm_naive_kernel<<<(unsigned)((total + 255) / 256), 256, 0, stream>>>(x, wgt, bias, out, M, N, K);
  }
}